// Round 9
// baseline (227.396 us; speedup 1.0000x reference)
//
#include <hip/hip_runtime.h>
#include <stdint.h>

// Problem constants
#define B_BATCH 2048     // batch rows (softmax columns here)
#define D_K     128      // embedding dim = GEMM K
#define N_ENT   100000   // entities (LSE reduction axis)
#define TROWS   64       // E rows per LDS tile (double-buffered)
#define NTILES  ((N_ENT + TROWS - 1) / TROWS)   // 1563
#define N_PAD   (NTILES * TROWS)                // 100032
#define ESPLIT  128      // entity stripes (16 per XCD)
#define NCG     8        // col groups of 256 cols (4 waves x 64)
#define LOG2E_F 1.4426950408889634f

#if __has_builtin(__builtin_amdgcn_exp2f)
#define FEXP2(x) __builtin_amdgcn_exp2f(x)   // raw v_exp_f32 (no libm fixup)
#else
#define FEXP2(x) exp2f(x)
#endif

typedef __attribute__((ext_vector_type(8))) __bf16 bf16x8;
typedef __attribute__((ext_vector_type(8))) short  short8;
typedef __attribute__((ext_vector_type(4))) float  f32x4;
typedef __attribute__((ext_vector_type(4))) unsigned int u32x4;

__device__ __forceinline__ short f2bf(float x) {
  // RNE fp32 -> bf16
  unsigned int u = __float_as_uint(x);
  unsigned int r = (u + 0x7fffu + ((u >> 16) & 1u)) >> 16;
  return (short)r;
}

__device__ __forceinline__ short8 pack8(f32x4 a, f32x4 b) {
  short8 v;
  v[0] = f2bf(a[0]); v[1] = f2bf(a[1]); v[2] = f2bf(a[2]); v[3] = f2bf(a[3]);
  v[4] = f2bf(b[0]); v[5] = f2bf(b[1]); v[6] = f2bf(b[2]); v[7] = f2bf(b[3]);
  return v;
}

// Truncating fp32->bf16 pack: 1 v_perm_b32 per 2 elems (no rounding bias
// concern for E: truncation error ~2^-9 relative, sign-random across k -> no
// systematic LSE shift; X keeps RNE).
__device__ __forceinline__ short8 pack8t(f32x4 a, f32x4 b) {
  u32x4 w;
  w[0] = __builtin_amdgcn_perm(__float_as_uint(a[1]), __float_as_uint(a[0]), 0x07060302u);
  w[1] = __builtin_amdgcn_perm(__float_as_uint(a[3]), __float_as_uint(a[2]), 0x07060302u);
  w[2] = __builtin_amdgcn_perm(__float_as_uint(b[1]), __float_as_uint(b[0]), 0x07060302u);
  w[3] = __builtin_amdgcn_perm(__float_as_uint(b[3]), __float_as_uint(b[2]), 0x07060302u);
  return __builtin_bit_cast(short8, w);
}

// ---------------------------------------------------------------------------
// Prep (grid = N_PAD*16 threads):
//  - Eb = trunc-bf16(E) stored PRE-SWIZZLED (granule s -> s ^ (row&7); rule 21:
//    linear global_load_lds dest + inverse-swizzled source + swizzled read).
//    Pad rows >= N_ENT zeroed.
//  - Xb = RNE-bf16(X); biasL = bias*log2e (-1e30 padding); S = 0.
//  - tdot[b] = fp32-exact dot(X[b], E[y[b]]) + bias[y[b]]  (hoisted out of
//    the former 85us single-block finish kernel; 16 threads/row).
// ---------------------------------------------------------------------------
__global__ __launch_bounds__(256)
void prep_kernel(const float* __restrict__ X, const float* __restrict__ E,
                 const float* __restrict__ bias, const int* __restrict__ y,
                 unsigned short* __restrict__ Xb, unsigned short* __restrict__ Eb,
                 float* __restrict__ biasL, float* __restrict__ S,
                 float* __restrict__ tdot)
{
  int tid = blockIdx.x * 256 + threadIdx.x;     // 0 .. N_PAD*16-1
  if (Eb) {
    int row = tid >> 4, s = tid & 15;           // row < N_PAD, 16B granule s
    f32x4 f0 = {0.f,0.f,0.f,0.f}, f1 = {0.f,0.f,0.f,0.f};
    if (row < N_ENT) {
      const float* src = E + (size_t)row * D_K + s * 8;
      f0 = *(const f32x4*)src;
      f1 = *(const f32x4*)(src + 4);
    }
    int sg = s ^ (row & 7);                     // pre-swizzle granule
    *(short8*)(Eb + (size_t)row * D_K + sg * 8) = pack8t(f0, f1);
  }
  if (tid < B_BATCH * D_K / 8) {
    int i = tid * 8;
    f32x4 a = *(const f32x4*)(X + i), b = *(const f32x4*)(X + i + 4);
    *(short8*)(Xb + i) = pack8(a, b);
  }
  if (tid < B_BATCH * 16) {                     // exact target logit
    int b = tid >> 4, sl = tid & 15;
    int yb = y[b];
    const float* xr = X + (size_t)b  * D_K + sl * 8;
    const float* er = E + (size_t)yb * D_K + sl * 8;
    f32x4 a0 = *(const f32x4*)xr,      a1 = *(const f32x4*)(xr + 4);
    f32x4 e0 = *(const f32x4*)er,      e1 = *(const f32x4*)(er + 4);
    float d = a0[0]*e0[0] + a0[1]*e0[1] + a0[2]*e0[2] + a0[3]*e0[3]
            + a1[0]*e1[0] + a1[1]*e1[1] + a1[2]*e1[2] + a1[3]*e1[3];
    #pragma unroll
    for (int sh = 1; sh <= 8; sh <<= 1) d += __shfl_xor(d, sh);
    if (sl == 0) tdot[b] = d + bias[yb];
  }
  if (tid < N_PAD) biasL[tid] = (tid < N_ENT) ? bias[tid] * LOG2E_F : -1e30f;
  if (tid < B_BATCH) S[tid] = 0.f;
}

// ---------------------------------------------------------------------------
// Main kernel. Grid = ESPLIT x NCG = 1024 blocks (4/CU), 4 waves.
//  - Round-8 post-mortem: LDS READ BW was the wall (every wave reads the
//    whole tile; C=128 -> 1.6 GB ~ 23us + 6.4M conflict cycles). C=256
//    (64 cols/wave) halves LDS reads/conflicts and doubles MFMA:ds_read.
//  - XCD decode: bid = q*64 + cg*8 + xcd -> stripe = xcd*16 + q. The 8
//    cg-blocks of a stripe share an XCD + a 64-bid dispatch window.
//  - Regs: Breg 64 + A 16 + acc 16 (AGPR) + misc ~20 ≈ 116 unified ≤ 128
//    -> 4 waves/SIMD at __launch_bounds__(256,4).
//  - Double-buffered 2x16KB LDS, ONE barrier per tile; next tile's
//    global_load_lds issued right after the barrier (T3-minimum schedule).
//  - Per 16-row chunk: 4 ds_read_b128 (A, XOR-swizzled), 16 MFMA,
//    16 raw v_exp_f32 into register running sums rs[4].
// ---------------------------------------------------------------------------
template<bool PRE>
__global__ __launch_bounds__(256, 4)
void fused_kernel(const unsigned short* __restrict__ Xb,  // [2048][128] bf16
                  const unsigned short* __restrict__ Eb,  // [N_PAD][128] bf16 swz (PRE)
                  const float* __restrict__ Ef,           // [100000][128] fp32 (!PRE)
                  const float* __restrict__ biasL,        // [N_PAD] bias*log2e
                  float* __restrict__ S)                  // [2048] atomic sums
{
  __shared__ __align__(16) unsigned short tile[2][TROWS * D_K];  // 2 x 16 KB

  const int bid    = blockIdx.x;
  const int stripe = (bid & 7) * 16 + (bid >> 6);   // 0..127
  const int cg     = (bid >> 3) & 7;                // 0..7
  const int t    = threadIdx.x;
  const int lane = t & 63;
  const int w    = t >> 6;
  const int lg   = lane >> 4;           // 0..3
  const int l15  = lane & 15;
  const int col0 = cg * 256 + w * 64;   // wave's first batch col

  // ---- resident B fragments: cols col0 + nj*16 + l15, k = kk*32 + lg*8 ----
  bf16x8 Breg[4][4];
  #pragma unroll
  for (int nj = 0; nj < 4; ++nj)
    #pragma unroll
    for (int kk = 0; kk < 4; ++kk)
      Breg[nj][kk] = __builtin_bit_cast(bf16x8,
          *(const short8*)(Xb + (size_t)(col0 + nj * 16 + l15) * D_K
                              + kk * 32 + lg * 8));

  float rs[4] = {0.f, 0.f, 0.f, 0.f};

  // PRE staging: wave w covers tile rows [w*16, w*16+16); 4 x global_load_lds
  // dwordx4 (linear dest = base + lane*16; source already swizzled).
  auto STAGE = [&](int buf, int g) {
    #pragma unroll
    for (int i = 0; i < 4; ++i) {
      const unsigned short* gp =
          Eb + ((size_t)g * TROWS + w * 16 + i * 4) * D_K + lane * 8;
      unsigned short* lp = &tile[buf][(w * 16 + i * 4) * D_K];
      __builtin_amdgcn_global_load_lds(
          (const __attribute__((address_space(1))) void*)gp,
          (__attribute__((address_space(3))) void*)lp, 16, 0, 0);
    }
  };

  // !PRE fallback staging (safety path if ws too small; not perf-tuned).
  f32x4 R[8];
  auto GLOAD = [&](int g) {
    #pragma unroll
    for (int i = 0; i < 4; ++i) {
      int gr = g * TROWS + w * 16 + i * 4 + lg;
      f32x4 z = {0.f,0.f,0.f,0.f};
      R[2*i] = z; R[2*i+1] = z;
      if (gr < N_ENT) {
        const float* src = Ef + (size_t)gr * D_K + l15 * 8;
        R[2*i]   = *(const f32x4*)src;
        R[2*i+1] = *(const f32x4*)(src + 4);
      }
    }
  };
  auto WRITE = [&](int buf) {
    #pragma unroll
    for (int i = 0; i < 4; ++i) {
      int rl = w * 16 + i * 4 + lg;
      int off = rl * D_K + ((l15 * 8) ^ ((rl & 7) << 3));
      *(short8*)&tile[buf][off] = pack8(R[2*i], R[2*i+1]);
    }
  };

  int cur = 0;
  if (PRE) STAGE(0, stripe); else GLOAD(stripe);

  for (int g = stripe; g < NTILES; g += ESPLIT) {
    const int gn = g + ESPLIT;
    if (PRE) {
      __syncthreads();                  // drains vmcnt -> tile[cur] ready;
                                        // prev readers of tile[cur^1] done
      if (gn < NTILES) STAGE(cur ^ 1, gn);
    } else {
      WRITE(cur);
      if (gn < NTILES) GLOAD(gn);
      __syncthreads();
    }

    const float* blp = biasL + g * TROWS;
    #pragma unroll
    for (int c = 0; c < 4; ++c) {
      f32x4 bl = *(const f32x4*)(blp + c * 16 + lg * 4);
      bf16x8 A[4];
      #pragma unroll
      for (int kk = 0; kk < 4; ++kk) {
        int off = (c * 16 + l15) * D_K + (((kk * 32) + lg * 8) ^ ((l15 & 7) << 3));
        A[kk] = __builtin_bit_cast(bf16x8, *(const short8*)&tile[cur][off]);
      }
      f32x4 acc[4];
      #pragma unroll
      for (int nj = 0; nj < 4; ++nj) acc[nj] = (f32x4){0.f, 0.f, 0.f, 0.f};
      #pragma unroll
      for (int kk = 0; kk < 4; ++kk)
        #pragma unroll
        for (int nj = 0; nj < 4; ++nj)
          acc[nj] = __builtin_amdgcn_mfma_f32_16x16x32_bf16(
              A[kk], Breg[nj][kk], acc[nj], 0, 0, 0);
      // D layout: col = lane&15, row = c*16 + lg*4 + ri  [m89/m91]
      #pragma unroll
      for (int nj = 0; nj < 4; ++nj) {
        float e0 = FEXP2(fmaf(acc[nj][0], LOG2E_F, bl[0]));
        float e1 = FEXP2(fmaf(acc[nj][1], LOG2E_F, bl[1]));
        float e2 = FEXP2(fmaf(acc[nj][2], LOG2E_F, bl[2]));
        float e3 = FEXP2(fmaf(acc[nj][3], LOG2E_F, bl[3]));
        rs[nj] += (e0 + e1) + (e2 + e3);
      }
    }
    cur ^= 1;
  }

  // ---- finish: fold the 4 lg groups, one atomic per column ----
  #pragma unroll
  for (int nj = 0; nj < 4; ++nj) {
    float s = rs[nj];
    s += __shfl_xor(s, 16);
    s += __shfl_xor(s, 32);
    if (lane < 16) atomicAdd(&S[col0 + nj * 16 + lane], s);
  }
}

// ---------------------------------------------------------------------------
// Final (single block): loss_b = ln2*log2(S_b) - tdot_b; mean -> out[0].
// ---------------------------------------------------------------------------
__global__ __launch_bounds__(256)
void final_kernel(const float* __restrict__ S, const float* __restrict__ tdot,
                  float* __restrict__ out)
{
  __shared__ float wsum[4];
  int t = threadIdx.x;
  float acc = 0.f;
  #pragma unroll
  for (int j = 0; j < B_BATCH / 256; ++j) {
    int b = j * 256 + t;
    acc += 0.6931471805599453f * log2f(S[b]) - tdot[b];
  }
  #pragma unroll
  for (int sh = 1; sh <= 32; sh <<= 1) acc += __shfl_xor(acc, sh);
  if ((t & 63) == 0) wsum[t >> 6] = acc;
  __syncthreads();
  if (t == 0) out[0] = (wsum[0] + wsum[1] + wsum[2] + wsum[3]) / (float)B_BATCH;
}

extern "C" void kernel_launch(void* const* d_in, const int* in_sizes, int n_in,
                              void* d_out, int out_size, void* d_ws, size_t ws_size,
                              hipStream_t stream)
{
  (void)in_sizes; (void)n_in; (void)out_size;
  const float* X    = (const float*)d_in[0];   // entity_embeddings [2048,128]
  const float* E    = (const float*)d_in[1];   // entity_embs [100000,128]
  const float* bias = (const float*)d_in[2];   // rec_entity_bias [100000]
  const int*   y    = (const int*)d_in[3];     // labels [2048]
  float* out = (float*)d_out;

  // ws layout: S f32[2048] | tdot f32[2048] | Xb bf16[2048*128] |
  //            biasL f32[N_PAD] | Eb bf16[N_PAD*128]
  char* p = (char*)d_ws;
  float*          Sacc  = (float*)p;                 p += (size_t)B_BATCH * 4;
  float*          tdot  = (float*)p;                 p += (size_t)B_BATCH * 4;
  unsigned short* Xb    = (unsigned short*)p;        p += (size_t)B_BATCH * D_K * 2;
  float*          biasL = (float*)p;                 p += (size_t)N_PAD * 4;
  unsigned short* Eb    = (unsigned short*)p;        p += (size_t)N_PAD * D_K * 2;
  const size_t need = (size_t)(p - (char*)d_ws);
  const bool pre = ws_size >= need;

  prep_kernel<<<N_PAD * 16 / 256, 256, 0, stream>>>(X, E, bias, y, Xb,
                                                    pre ? Eb : nullptr,
                                                    biasL, Sacc, tdot);
  if (pre)
    fused_kernel<true><<<ESPLIT * NCG, 256, 0, stream>>>(Xb, Eb, E, biasL, Sacc);
  else
    fused_kernel<false><<<ESPLIT * NCG, 256, 0, stream>>>(Xb, Eb, E, biasL, Sacc);
  final_kernel<<<1, 256, 0, stream>>>(Sacc, tdot, out);
}

// Round 11
// 152.770 us; speedup vs baseline: 1.4885x; 1.4885x over previous
//
#include <hip/hip_runtime.h>
#include <stdint.h>

// Problem constants
#define B_BATCH 2048     // batch rows (softmax columns here)
#define D_K     128      // embedding dim = GEMM K
#define N_ENT   100000   // entities (LSE reduction axis)
#define TROWS   64       // E rows per LDS tile (double-buffered)
#define NTILES  ((N_ENT + TROWS - 1) / TROWS)   // 1563
#define N_PAD   (NTILES * TROWS)                // 100032
#define ESPLIT  128      // entity stripes (16 per XCD)
#define NCG     8        // col groups of 256 cols (4 waves x 64)
#define LOG2E_F 1.4426950408889634f

#if __has_builtin(__builtin_amdgcn_exp2f)
#define FEXP2(x) __builtin_amdgcn_exp2f(x)   // raw v_exp_f32 (no libm fixup)
#else
#define FEXP2(x) exp2f(x)
#endif

typedef __attribute__((ext_vector_type(8))) __bf16 bf16x8;
typedef __attribute__((ext_vector_type(8))) short  short8;
typedef __attribute__((ext_vector_type(4))) float  f32x4;
typedef __attribute__((ext_vector_type(4))) unsigned int u32x4;

__device__ __forceinline__ short f2bf(float x) {
  // RNE fp32 -> bf16
  unsigned int u = __float_as_uint(x);
  unsigned int r = (u + 0x7fffu + ((u >> 16) & 1u)) >> 16;
  return (short)r;
}

__device__ __forceinline__ short8 pack8(f32x4 a, f32x4 b) {
  short8 v;
  v[0] = f2bf(a[0]); v[1] = f2bf(a[1]); v[2] = f2bf(a[2]); v[3] = f2bf(a[3]);
  v[4] = f2bf(b[0]); v[5] = f2bf(b[1]); v[6] = f2bf(b[2]); v[7] = f2bf(b[3]);
  return v;
}

// Truncating fp32->bf16 pack: 1 v_perm_b32 per 2 elems.
__device__ __forceinline__ short8 pack8t(f32x4 a, f32x4 b) {
  u32x4 w;
  w[0] = __builtin_amdgcn_perm(__float_as_uint(a[1]), __float_as_uint(a[0]), 0x07060302u);
  w[1] = __builtin_amdgcn_perm(__float_as_uint(a[3]), __float_as_uint(a[2]), 0x07060302u);
  w[2] = __builtin_amdgcn_perm(__float_as_uint(b[1]), __float_as_uint(b[0]), 0x07060302u);
  w[3] = __builtin_amdgcn_perm(__float_as_uint(b[3]), __float_as_uint(b[2]), 0x07060302u);
  return __builtin_bit_cast(short8, w);
}

// ---------------------------------------------------------------------------
// Prep (grid = N_PAD*16 threads):
//  - Eb = trunc-bf16(E) stored PRE-SWIZZLED (granule s -> s ^ (row&7); rule 21:
//    linear global_load_lds dest + inverse-swizzled source + swizzled read).
//    Pad rows >= N_ENT zeroed.
//  - Xb = RNE-bf16(X); biasL = bias*log2e (-1e30 padding); S = 0.
//  - tdot[b] = fp32-exact dot(X[b], E[y[b]]) + bias[y[b]]  (hoisted out of
//    the former 85us single-block finish kernel; 16 threads/row).
// ---------------------------------------------------------------------------
__global__ __launch_bounds__(256)
void prep_kernel(const float* __restrict__ X, const float* __restrict__ E,
                 const float* __restrict__ bias, const int* __restrict__ y,
                 unsigned short* __restrict__ Xb, unsigned short* __restrict__ Eb,
                 float* __restrict__ biasL, float* __restrict__ S,
                 float* __restrict__ tdot)
{
  int tid = blockIdx.x * 256 + threadIdx.x;     // 0 .. N_PAD*16-1
  if (Eb) {
    int row = tid >> 4, s = tid & 15;           // row < N_PAD, 16B granule s
    f32x4 f0 = {0.f,0.f,0.f,0.f}, f1 = {0.f,0.f,0.f,0.f};
    if (row < N_ENT) {
      const float* src = E + (size_t)row * D_K + s * 8;
      f0 = *(const f32x4*)src;
      f1 = *(const f32x4*)(src + 4);
    }
    int sg = s ^ (row & 7);                     // pre-swizzle granule
    *(short8*)(Eb + (size_t)row * D_K + sg * 8) = pack8t(f0, f1);
  }
  if (tid < B_BATCH * D_K / 8) {
    int i = tid * 8;
    f32x4 a = *(const f32x4*)(X + i), b = *(const f32x4*)(X + i + 4);
    *(short8*)(Xb + i) = pack8(a, b);
  }
  if (tid < B_BATCH * 16) {                     // exact target logit
    int b = tid >> 4, sl = tid & 15;
    int yb = y[b];
    const float* xr = X + (size_t)b  * D_K + sl * 8;
    const float* er = E + (size_t)yb * D_K + sl * 8;
    f32x4 a0 = *(const f32x4*)xr,      a1 = *(const f32x4*)(xr + 4);
    f32x4 e0 = *(const f32x4*)er,      e1 = *(const f32x4*)(er + 4);
    float d = a0[0]*e0[0] + a0[1]*e0[1] + a0[2]*e0[2] + a0[3]*e0[3]
            + a1[0]*e1[0] + a1[1]*e1[1] + a1[2]*e1[2] + a1[3]*e1[3];
    #pragma unroll
    for (int sh = 1; sh <= 8; sh <<= 1) d += __shfl_xor(d, sh);
    if (sl == 0) tdot[b] = d + bias[yb];
  }
  if (tid < N_PAD) biasL[tid] = (tid < N_ENT) ? bias[tid] * LOG2E_F : -1e30f;
  if (tid < B_BATCH) S[tid] = 0.f;
}

// ---------------------------------------------------------------------------
// Main kernel. Grid = ESPLIT x NCG = 1024 blocks, 4 waves.
//  - C=256 (64 cols/wave): halves LDS reads/conflicts vs C=128; 16 MFMA per
//    4 ds_read_b128.
//  - ROUND-9 POST-MORTEM: __launch_bounds__(256,4) capped regs at 128 but the
//    live set is ~135 -> compiler spilled Breg to SCRATCH (WRITE_SIZE 175MB,
//    456MB HBM/dispatch, 2x slower). Relaxed to (256,3): 170-reg cap fits
//    Breg 64 + A 16 + acc 16 (AGPR) + addressing with headroom; measured
//    occupancy at the 4-wave bound was only 33% anyway, so ~nothing lost.
//  - XCD decode: bid = q*64 + cg*8 + xcd -> stripe = xcd*16 + q. The 8
//    cg-blocks of a stripe share an XCD + a 64-bid dispatch window.
//  - Double-buffered 2x16KB LDS, ONE barrier per tile; next tile's
//    global_load_lds issued right after the barrier (T3-minimum schedule).
//  - Per 16-row chunk: 4 ds_read_b128 (A, XOR-swizzled), 16 MFMA,
//    16 raw v_exp_f32 into register running sums rs[4].
// ---------------------------------------------------------------------------
template<bool PRE>
__global__ __launch_bounds__(256, 3)
void fused_kernel(const unsigned short* __restrict__ Xb,  // [2048][128] bf16
                  const unsigned short* __restrict__ Eb,  // [N_PAD][128] bf16 swz (PRE)
                  const float* __restrict__ Ef,           // [100000][128] fp32 (!PRE)
                  const float* __restrict__ biasL,        // [N_PAD] bias*log2e
                  float* __restrict__ S)                  // [2048] atomic sums
{
  __shared__ __align__(16) unsigned short tile[2][TROWS * D_K];  // 2 x 16 KB

  const int bid    = blockIdx.x;
  const int stripe = (bid & 7) * 16 + (bid >> 6);   // 0..127
  const int cg     = (bid >> 3) & 7;                // 0..7
  const int t    = threadIdx.x;
  const int lane = t & 63;
  const int w    = t >> 6;
  const int lg   = lane >> 4;           // 0..3
  const int l15  = lane & 15;
  const int col0 = cg * 256 + w * 64;   // wave's first batch col

  // ---- resident B fragments: cols col0 + nj*16 + l15, k = kk*32 + lg*8 ----
  bf16x8 Breg[4][4];
  #pragma unroll
  for (int nj = 0; nj < 4; ++nj)
    #pragma unroll
    for (int kk = 0; kk < 4; ++kk)
      Breg[nj][kk] = __builtin_bit_cast(bf16x8,
          *(const short8*)(Xb + (size_t)(col0 + nj * 16 + l15) * D_K
                              + kk * 32 + lg * 8));

  float rs[4] = {0.f, 0.f, 0.f, 0.f};

  // PRE staging: wave w covers tile rows [w*16, w*16+16); 4 x global_load_lds
  // dwordx4 (linear dest = base + lane*16; source already swizzled).
  auto STAGE = [&](int buf, int g) {
    #pragma unroll
    for (int i = 0; i < 4; ++i) {
      const unsigned short* gp =
          Eb + ((size_t)g * TROWS + w * 16 + i * 4) * D_K + lane * 8;
      unsigned short* lp = &tile[buf][(w * 16 + i * 4) * D_K];
      __builtin_amdgcn_global_load_lds(
          (const __attribute__((address_space(1))) void*)gp,
          (__attribute__((address_space(3))) void*)lp, 16, 0, 0);
    }
  };

  // !PRE fallback staging (safety path if ws too small; not perf-tuned).
  f32x4 R[8];
  auto GLOAD = [&](int g) {
    #pragma unroll
    for (int i = 0; i < 4; ++i) {
      int gr = g * TROWS + w * 16 + i * 4 + lg;
      f32x4 z = {0.f,0.f,0.f,0.f};
      R[2*i] = z; R[2*i+1] = z;
      if (gr < N_ENT) {
        const float* src = Ef + (size_t)gr * D_K + l15 * 8;
        R[2*i]   = *(const f32x4*)src;
        R[2*i+1] = *(const f32x4*)(src + 4);
      }
    }
  };
  auto WRITE = [&](int buf) {
    #pragma unroll
    for (int i = 0; i < 4; ++i) {
      int rl = w * 16 + i * 4 + lg;
      int off = rl * D_K + ((l15 * 8) ^ ((rl & 7) << 3));
      *(short8*)&tile[buf][off] = pack8(R[2*i], R[2*i+1]);
    }
  };

  int cur = 0;
  if (PRE) STAGE(0, stripe); else GLOAD(stripe);

  for (int g = stripe; g < NTILES; g += ESPLIT) {
    const int gn = g + ESPLIT;
    if (PRE) {
      __syncthreads();                  // drains vmcnt -> tile[cur] ready;
                                        // prev readers of tile[cur^1] done
      if (gn < NTILES) STAGE(cur ^ 1, gn);
    } else {
      WRITE(cur);
      if (gn < NTILES) GLOAD(gn);
      __syncthreads();
    }

    const float* blp = biasL + g * TROWS;
    #pragma unroll
    for (int c = 0; c < 4; ++c) {
      f32x4 bl = *(const f32x4*)(blp + c * 16 + lg * 4);
      bf16x8 A[4];
      #pragma unroll
      for (int kk = 0; kk < 4; ++kk) {
        int off = (c * 16 + l15) * D_K + (((kk * 32) + lg * 8) ^ ((l15 & 7) << 3));
        A[kk] = __builtin_bit_cast(bf16x8, *(const short8*)&tile[cur][off]);
      }
      f32x4 acc[4];
      #pragma unroll
      for (int nj = 0; nj < 4; ++nj) acc[nj] = (f32x4){0.f, 0.f, 0.f, 0.f};
      #pragma unroll
      for (int kk = 0; kk < 4; ++kk)
        #pragma unroll
        for (int nj = 0; nj < 4; ++nj)
          acc[nj] = __builtin_amdgcn_mfma_f32_16x16x32_bf16(
              A[kk], Breg[nj][kk], acc[nj], 0, 0, 0);
      // D layout: col = lane&15, row = c*16 + lg*4 + ri  [m89/m91]
      #pragma unroll
      for (int nj = 0; nj < 4; ++nj) {
        float e0 = FEXP2(fmaf(acc[nj][0], LOG2E_F, bl[0]));
        float e1 = FEXP2(fmaf(acc[nj][1], LOG2E_F, bl[1]));
        float e2 = FEXP2(fmaf(acc[nj][2], LOG2E_F, bl[2]));
        float e3 = FEXP2(fmaf(acc[nj][3], LOG2E_F, bl[3]));
        rs[nj] += (e0 + e1) + (e2 + e3);
      }
    }
    cur ^= 1;
  }

  // ---- finish: fold the 4 lg groups, one atomic per column ----
  #pragma unroll
  for (int nj = 0; nj < 4; ++nj) {
    float s = rs[nj];
    s += __shfl_xor(s, 16);
    s += __shfl_xor(s, 32);
    if (lane < 16) atomicAdd(&S[col0 + nj * 16 + lane], s);
  }
}

// ---------------------------------------------------------------------------
// Final (single block): loss_b = ln2*log2(S_b) - tdot_b; mean -> out[0].
// ---------------------------------------------------------------------------
__global__ __launch_bounds__(256)
void final_kernel(const float* __restrict__ S, const float* __restrict__ tdot,
                  float* __restrict__ out)
{
  __shared__ float wsum[4];
  int t = threadIdx.x;
  float acc = 0.f;
  #pragma unroll
  for (int j = 0; j < B_BATCH / 256; ++j) {
    int b = j * 256 + t;
    acc += 0.6931471805599453f * log2f(S[b]) - tdot[b];
  }
  #pragma unroll
  for (int sh = 1; sh <= 32; sh <<= 1) acc += __shfl_xor(acc, sh);
  if ((t & 63) == 0) wsum[t >> 6] = acc;
  __syncthreads();
  if (t == 0) out[0] = (wsum[0] + wsum[1] + wsum[2] + wsum[3]) / (float)B_BATCH;
}

extern "C" void kernel_launch(void* const* d_in, const int* in_sizes, int n_in,
                              void* d_out, int out_size, void* d_ws, size_t ws_size,
                              hipStream_t stream)
{
  (void)in_sizes; (void)n_in; (void)out_size;
  const float* X    = (const float*)d_in[0];   // entity_embeddings [2048,128]
  const float* E    = (const float*)d_in[1];   // entity_embs [100000,128]
  const float* bias = (const float*)d_in[2];   // rec_entity_bias [100000]
  const int*   y    = (const int*)d_in[3];     // labels [2048]
  float* out = (float*)d_out;

  // ws layout: S f32[2048] | tdot f32[2048] | Xb bf16[2048*128] |
  //            biasL f32[N_PAD] | Eb bf16[N_PAD*128]
  char* p = (char*)d_ws;
  float*          Sacc  = (float*)p;                 p += (size_t)B_BATCH * 4;
  float*          tdot  = (float*)p;                 p += (size_t)B_BATCH * 4;
  unsigned short* Xb    = (unsigned short*)p;        p += (size_t)B_BATCH * D_K * 2;
  float*          biasL = (float*)p;                 p += (size_t)N_PAD * 4;
  unsigned short* Eb    = (unsigned short*)p;        p += (size_t)N_PAD * D_K * 2;
  const size_t need = (size_t)(p - (char*)d_ws);
  const bool pre = ws_size >= need;

  prep_kernel<<<N_PAD * 16 / 256, 256, 0, stream>>>(X, E, bias, y, Xb,
                                                    pre ? Eb : nullptr,
                                                    biasL, Sacc, tdot);
  if (pre)
    fused_kernel<true><<<ESPLIT * NCG, 256, 0, stream>>>(Xb, Eb, E, biasL, Sacc);
  else
    fused_kernel<false><<<ESPLIT * NCG, 256, 0, stream>>>(Xb, Eb, E, biasL, Sacc);
  final_kernel<<<1, 256, 0, stream>>>(Sacc, tdot, out);
}